// Round 2
// baseline (625.358 us; speedup 1.0000x reference)
//
#include <hip/hip_runtime.h>
#include <cstdint>

#define N_NODES 50000
#define N_EDGES 800000
#define IN_DIM  256
#define HID     128
#define T_STEPS 8

// ---------- float <-> orderable uint encoding for atomic min/max ----------
static __device__ __forceinline__ unsigned int enc_f(float f) {
    unsigned int u = __float_as_uint(f);
    return (u & 0x80000000u) ? ~u : (u | 0x80000000u);
}
static __device__ __forceinline__ float dec_f(unsigned int u) {
    unsigned int b = (u & 0x80000000u) ? (u ^ 0x80000000u) : ~u;
    return __uint_as_float(b);
}

// ---------- CSR build ----------
__global__ void k_count(const int* __restrict__ dst, int* __restrict__ counts) {
    int e = blockIdx.x * blockDim.x + threadIdx.x;
    if (e < N_EDGES) atomicAdd(&counts[dst[e]], 1);
}

__global__ void k_scan1(const int* __restrict__ counts, int* __restrict__ row_tmp,
                        int* __restrict__ blocksum) {
    __shared__ int sh[256];
    int t = threadIdx.x, i = blockIdx.x * 256 + t;
    int c = (i < N_NODES) ? counts[i] : 0;
    sh[t] = c; __syncthreads();
    for (int off = 1; off < 256; off <<= 1) {
        int val = (t >= off) ? sh[t - off] : 0;
        __syncthreads();
        sh[t] += val;
        __syncthreads();
    }
    if (i < N_NODES) row_tmp[i] = sh[t] - c;     // exclusive
    if (t == 255) blocksum[blockIdx.x] = sh[255];
}

__global__ void k_scan2(const int* __restrict__ blocksum, int* __restrict__ blockoff,
                        int nb, int* __restrict__ row_ptr) {
    if (threadIdx.x == 0) {
        int acc = 0;
        for (int b = 0; b < nb; ++b) { blockoff[b] = acc; acc += blocksum[b]; }
        row_ptr[N_NODES] = acc;   // == N_EDGES
    }
}

__global__ void k_scan3(const int* __restrict__ row_tmp, const int* __restrict__ blockoff,
                        int* __restrict__ row_ptr) {
    int i = blockIdx.x * blockDim.x + threadIdx.x;
    if (i < N_NODES) row_ptr[i] = row_tmp[i] + blockoff[i >> 8];
}

// fill CSR slots: eid (4B) + merged (src, attr) int2 (8B) — 2 scatters/edge
__global__ void k_fill(const int* __restrict__ dst, const int* __restrict__ src,
                       const float* __restrict__ attr,
                       const int* __restrict__ row_ptr, int* __restrict__ cursor,
                       int* __restrict__ eid, int2* __restrict__ edata) {
    int e = blockIdx.x * blockDim.x + threadIdx.x;
    if (e >= N_EDGES) return;
    int d = dst[e];
    int p = row_ptr[d] + atomicAdd(&cursor[d], 1);
    eid[p]   = e;
    edata[p] = make_int2(src[e], __float_as_int(attr[e]));
}

// wave-wide bitonic sort per node by eid: restores np.add.at ascending order
__global__ __launch_bounds__(256) void k_bsort(const int* __restrict__ row_ptr,
                                               int* __restrict__ eid,
                                               int2* __restrict__ edata) {
    int node = blockIdx.x * 4 + (threadIdx.x >> 6);
    int l = threadIdx.x & 63;
    int beg = row_ptr[node], end = row_ptr[node + 1], cnt = end - beg;
    if (cnt <= 1) return;
    if (cnt <= 64) {
        int key = 0x7FFFFFFF, sv = 0, av = 0;
        if (l < cnt) { key = eid[beg + l]; int2 d = edata[beg + l]; sv = d.x; av = d.y; }
        #pragma unroll
        for (int k = 2; k <= 64; k <<= 1) {
            for (int j = k >> 1; j > 0; j >>= 1) {
                int pk = __shfl_xor(key, j);
                int ps = __shfl_xor(sv, j);
                int pa = __shfl_xor(av, j);
                bool lower = (l & j) == 0;
                bool asc   = (l & k) == 0;
                bool take_min = (lower == asc);
                bool take = take_min ? (pk < key) : (pk > key);
                if (take) { key = pk; sv = ps; av = pa; }
            }
        }
        if (l < cnt) { eid[beg + l] = key; edata[beg + l] = make_int2(sv, av); }
    } else if (l == 0) {
        for (int i = beg + 1; i < end; ++i) {
            int ke = eid[i]; int2 kd = edata[i];
            int m = i - 1;
            while (m >= beg && eid[m] > ke) {
                eid[m+1] = eid[m]; edata[m+1] = edata[m]; --m;
            }
            eid[m+1] = ke; edata[m+1] = kd;
        }
    }
}

// ---------- tiled GEMM: 64 nodes x 128 feats per block, fused min/max ----------
__global__ __launch_bounds__(256) void k_gemm(const float* __restrict__ x,
                                              const float* __restrict__ W,
                                              const float* __restrict__ b,
                                              float* __restrict__ h,
                                              unsigned int* __restrict__ mn_e,
                                              unsigned int* __restrict__ mx_e) {
    __shared__ float Ws[32 * 128];
    __shared__ float xs[64 * 36];
    __shared__ float red_mn[8 * 128];
    __shared__ float red_mx[8 * 128];
    const int tid = threadIdx.x;
    const int n0 = blockIdx.x * 64;
    const int jt = tid & 31, nt = tid >> 5;
    const int j0 = jt * 4;

    float acc[8][4];
    #pragma unroll
    for (int a = 0; a < 8; ++a)
        #pragma unroll
        for (int c = 0; c < 4; ++c) acc[a][c] = 0.0f;

    const int ldn = tid >> 2;
    const int kq  = (tid & 3) * 8;
    const int xrow = (n0 + ldn < N_NODES) ? (n0 + ldn) : (N_NODES - 1);
    const float* xg = x + (size_t)xrow * IN_DIM;

    for (int kc = 0; kc < IN_DIM; kc += 32) {
        __syncthreads();
        float4 xa = *(const float4*)(xg + kc + kq);
        float4 xb = *(const float4*)(xg + kc + kq + 4);
        *(float4*)&xs[ldn * 36 + kq]     = xa;
        *(float4*)&xs[ldn * 36 + kq + 4] = xb;
        #pragma unroll
        for (int p = 0; p < 4; ++p) {
            int r = nt + p * 8;
            *(float4*)&Ws[r * 128 + j0] =
                *(const float4*)(W + (size_t)(kc + r) * HID + j0);
        }
        __syncthreads();
        const float* xbase = &xs[nt * 8 * 36];
        #pragma unroll 4
        for (int k = 0; k < 32; ++k) {
            float4 wf = *(const float4*)&Ws[k * 128 + j0];
            #pragma unroll
            for (int ni = 0; ni < 8; ++ni) {
                float xv = xbase[ni * 36 + k];
                acc[ni][0] = __fmaf_rn(xv, wf.x, acc[ni][0]);
                acc[ni][1] = __fmaf_rn(xv, wf.y, acc[ni][1]);
                acc[ni][2] = __fmaf_rn(xv, wf.z, acc[ni][2]);
                acc[ni][3] = __fmaf_rn(xv, wf.w, acc[ni][3]);
            }
        }
    }

    float4 bv = *(const float4*)(b + j0);
    float lmn[4], lmx[4];
    #pragma unroll
    for (int c = 0; c < 4; ++c) { lmn[c] = INFINITY; lmx[c] = -INFINITY; }
    #pragma unroll
    for (int ni = 0; ni < 8; ++ni) {
        acc[ni][0] = __fadd_rn(acc[ni][0], bv.x);
        acc[ni][1] = __fadd_rn(acc[ni][1], bv.y);
        acc[ni][2] = __fadd_rn(acc[ni][2], bv.z);
        acc[ni][3] = __fadd_rn(acc[ni][3], bv.w);
        #pragma unroll
        for (int c = 0; c < 4; ++c) {
            lmn[c] = fminf(lmn[c], acc[ni][c]);
            lmx[c] = fmaxf(lmx[c], acc[ni][c]);
        }
    }
    #pragma unroll
    for (int c = 0; c < 4; ++c) {
        red_mn[nt * 128 + j0 + c] = lmn[c];
        red_mx[nt * 128 + j0 + c] = lmx[c];
    }
    __syncthreads();
    if (tid < 128) {
        float mnv = red_mn[tid], mxv = red_mx[tid];
        #pragma unroll
        for (int r = 1; r < 8; ++r) {
            mnv = fminf(mnv, red_mn[r * 128 + tid]);
            mxv = fmaxf(mxv, red_mx[r * 128 + tid]);
        }
        atomicMin(&mn_e[tid], enc_f(mnv));
        atomicMax(&mx_e[tid], enc_f(mxv));
    }
    #pragma unroll
    for (int ni = 0; ni < 8; ++ni) {
        int n = n0 + nt * 8 + ni;
        if (n < N_NODES)
            *(float4*)&h[(size_t)n * HID + j0] =
                make_float4(acc[ni][0], acc[ni][1], acc[ni][2], acc[ni][3]);
    }
}

// ---------- init spike bitmask ----------
__global__ void k_init_bits(const int* __restrict__ spike_node, uint32_t* __restrict__ sb) {
    int n = blockIdx.x * blockDim.x + threadIdx.x;
    if (n >= N_NODES) return;
    uint32_t f = spike_node[n] ? 0xFFFFFFFFu : 0u;
    sb[(size_t)n * 4 + 0] = f;
    sb[(size_t)n * 4 + 1] = f;
    sb[(size_t)n * 4 + 2] = f;
    sb[(size_t)n * 4 + 3] = f;
}

// ---------- flag-array barrier, ZERO fences / ZERO acq_rel ----------
// R1 post-mortem: dur = W + 7*B(nblk); B(758)=49us, W=286us. The old gbar2's
// acq_rel arrivals + __threadfence pair force per-arrival L2 writeback &
// invalidate on this multi-XCD part -> later arrivals re-miss everything;
// cost scales with block count (628us @758blk -> 970us @1516blk, same total
// VALU cycles). Fix: software coherence. ALL cross-block data moves via
// RELAXED agent-scope atomics (LLC-homed, cross-XCD coherent -- the same
// mechanism gbar2's own poll loops already relied on). Arrival = one plain
// relaxed store (no RMW chain); block 0 aggregates; one `go` word broadcasts.
// Ordering: __syncthreads drains vmcnt(0) => all publish stores LLC-acked
// before the flag store issues; consumers gather only after observing go.
static __device__ __forceinline__ void fbar(int* bar, int nblk, int t) {
    int* flags = bar;            // [nblk] ints, monotonically increasing step ids
    int* go    = bar + 1900;     // separate line, past flags (nblk <= 1536)
    __syncthreads();             // all threads' prior stores acked (vmcnt 0)
    if (blockIdx.x == 0) {
        if (threadIdx.x == 0)
            __hip_atomic_store(&flags[0], t, __ATOMIC_RELAXED, __HIP_MEMORY_SCOPE_AGENT);
        for (;;) {
            int ok = 1;
            for (int i = (int)threadIdx.x; i < nblk; i += 256)
                ok &= (__hip_atomic_load(&flags[i], __ATOMIC_RELAXED,
                                         __HIP_MEMORY_SCOPE_AGENT) >= t);
            if (__syncthreads_and(ok)) break;
            __builtin_amdgcn_s_sleep(1);
        }
        if (threadIdx.x == 0)
            __hip_atomic_store(go, t, __ATOMIC_RELAXED, __HIP_MEMORY_SCOPE_AGENT);
        // __syncthreads_and already synchronized the block; proceed.
    } else {
        if (threadIdx.x == 0) {
            __hip_atomic_store(&flags[blockIdx.x], t, __ATOMIC_RELAXED,
                               __HIP_MEMORY_SCOPE_AGENT);
            while (__hip_atomic_load(go, __ATOMIC_RELAXED,
                                     __HIP_MEMORY_SCOPE_AGENT) < t)
                __builtin_amdgcn_s_sleep(4);
        }
        __syncthreads();
    }
}

// ---------- persistent fused 8-step LIF (templated variants) ----------
// R1: occupancy is NOT the lever (C @6blk/CU == A @3blk/CU timed; worse under
// profiler). Default back to A-shape (NPB=66, 758 blocks, 3/CU).
// Cross-block spike words: published and gathered with RELAXED agent atomics
// (sc-bit, LLC-coherent) so no fences are ever needed.
// Slot state arrays MUST stay fully unrolled (R4 errata: dynamic indexing
// demotes them to scratch -> 420 MB spill traffic).
template<int TNPB, int TNSLOT, int TECAP, int TPACK, int TMINW>
__global__ __launch_bounds__(256, TMINW) void k_lif_t(
    const int* __restrict__ row_ptr,
    const int2* __restrict__ edata,
    uint32_t* __restrict__ sbA,
    uint32_t* __restrict__ sbB,
    const float* __restrict__ h_raw,
    const unsigned int* __restrict__ mn_e,
    const unsigned int* __restrict__ mx_e,
    float* __restrict__ out,
    int* __restrict__ bar,
    int nblk)
{
    __shared__ int      lrp[TNPB + 1];
    __shared__ int      ed_src_l[TECAP];
    __shared__ float    ed_attr_l[TECAP];
    __shared__ uint32_t ed_wds[TPACK ? 1 : TECAP * 4];      // unpacked words
    __shared__ uint2    ed_pk[TPACK ? TECAP * 4 : 1];       // packed (attr,word)
    __shared__ uint32_t sbw[TNPB][4];

    const int tid = threadIdx.x;
    const int g   = tid >> 5;                 // node group 0..7
    const int ln  = tid & 31;                 // features 4ln..4ln+3
    const int n0  = blockIdx.x * TNPB;
    const int ncnt = min(TNPB, N_NODES - n0);
    const int w = ln >> 3, shb = (ln & 7) * 4;
    const size_t NH = (size_t)N_NODES * HID;

    if (tid <= ncnt) lrp[tid] = row_ptr[n0 + tid];
    __syncthreads();
    const int ebase = lrp[0];
    const int etot  = lrp[ncnt] - ebase;
    const bool inlds = (etot <= TECAP);
    if (inlds) {
        for (int i = tid; i < etot; i += 256) {
            int2 d = edata[ebase + i];
            ed_src_l[i]  = d.x;
            ed_attr_l[i] = __int_as_float(d.y);
        }
    }

    // per-lane normalization constants
    uint4 mnu = *(const uint4*)&mn_e[ln * 4];
    uint4 mxu = *(const uint4*)&mx_e[ln * 4];
    float mn0 = dec_f(mnu.x), mn1 = dec_f(mnu.y), mn2 = dec_f(mnu.z), mn3 = dec_f(mnu.w);
    float dd0 = __fadd_rn(__fsub_rn(dec_f(mxu.x), mn0), 1e-6f);
    float dd1 = __fadd_rn(__fsub_rn(dec_f(mxu.y), mn1), 1e-6f);
    float dd2 = __fadd_rn(__fsub_rn(dec_f(mxu.z), mn2), 1e-6f);
    float dd3 = __fadd_rn(__fsub_rn(dec_f(mxu.w), mn3), 1e-6f);

    // load + normalize h; init v, ref (registers, fully static indexing)
    float4 hs[TNSLOT], vs[TNSLOT];
    uint32_t rcs[TNSLOT];
    #pragma unroll
    for (int s = 0; s < TNSLOT; ++s) {
        hs[s] = make_float4(0.f, 0.f, 0.f, 0.f);
        vs[s] = make_float4(0.f, 0.f, 0.f, 0.f);
        rcs[s] = 0u;
        int m = s * 8 + g;
        if (m < ncnt) {
            size_t idx = (size_t)(n0 + m) * HID + ln * 4;
            float4 t = *(const float4*)&h_raw[idx];
            t.x = __fdiv_rn(__fsub_rn(t.x, mn0), dd0);
            t.y = __fdiv_rn(__fsub_rn(t.y, mn1), dd1);
            t.z = __fdiv_rn(__fsub_rn(t.z, mn2), dd2);
            t.w = __fdiv_rn(__fsub_rn(t.w, mn3), dd3);
            hs[s] = t;
        }
    }
    for (int i = tid; i < ncnt * 4; i += 256) ((uint32_t*)sbw)[i] = 0u;
    __syncthreads();

    for (int t = 0; t < T_STEPS; ++t) {
        const uint32_t* cur = (t & 1) ? sbB : sbA;
        uint32_t*       nxt = (t & 1) ? sbA : sbB;
        if (t > 0) fbar(bar, nblk, t);        // step t-1 publishes visible (LLC)

        if (inlds) {                          // stage this step's spike words
            for (int i = tid; i < etot; i += 256) {
                unsigned long long* sp =
                    (unsigned long long*)&cur[(size_t)ed_src_l[i] * 4];
                unsigned long long lo = __hip_atomic_load(
                    sp, __ATOMIC_RELAXED, __HIP_MEMORY_SCOPE_AGENT);
                unsigned long long hi = __hip_atomic_load(
                    sp + 1, __ATOMIC_RELAXED, __HIP_MEMORY_SCOPE_AGENT);
                uint4 wv;
                wv.x = (uint32_t)lo; wv.y = (uint32_t)(lo >> 32);
                wv.z = (uint32_t)hi; wv.w = (uint32_t)(hi >> 32);
                if (TPACK) {
                    uint32_t ab = __float_as_uint(ed_attr_l[i]);
                    ed_pk[i * 4 + 0] = make_uint2(ab, wv.x);
                    ed_pk[i * 4 + 1] = make_uint2(ab, wv.y);
                    ed_pk[i * 4 + 2] = make_uint2(ab, wv.z);
                    ed_pk[i * 4 + 3] = make_uint2(ab, wv.w);
                } else {
                    *(uint4*)&ed_wds[i * 4] = wv;
                }
            }
        }
        __syncthreads();

        #pragma unroll
        for (int s = 0; s < TNSLOT; ++s) {
            int m = s * 8 + g;
            if (m < ncnt) {
                float ag0 = 0.f, ag1 = 0.f, ag2 = 0.f, ag3 = 0.f;
                if (inlds) {
                    int lb = lrp[m] - ebase, le = lrp[m + 1] - ebase;
                    for (int i = lb; i < le; ++i) {       // ascending edge order
                        uint32_t u; float a;
                        if (TPACK) {
                            uint2 p = ed_pk[i * 4 + w];   // one ds_read_b64
                            a = __uint_as_float(p.x);
                            u = p.y;
                        } else {
                            u = ed_wds[i * 4 + w];
                            a = ed_attr_l[i];
                        }
                        uint32_t bits = (u >> shb) & 0xFu;
                        ag0 = __fadd_rn(ag0, (bits & 1u) ? a : 0.f);   // +0.0 exact
                        ag1 = __fadd_rn(ag1, (bits & 2u) ? a : 0.f);
                        ag2 = __fadd_rn(ag2, (bits & 4u) ? a : 0.f);
                        ag3 = __fadd_rn(ag3, (bits & 8u) ? a : 0.f);
                    }
                } else {                                  // overflow fallback
                    int lb = lrp[m], le = lrp[m + 1];
                    for (int i = lb; i < le; ++i) {
                        int2 d = edata[i];
                        uint32_t u = __hip_atomic_load(
                            (uint32_t*)&cur[(size_t)d.x * 4 + w],
                            __ATOMIC_RELAXED, __HIP_MEMORY_SCOPE_AGENT);
                        float a = __int_as_float(d.y);
                        uint32_t bits = (u >> shb) & 0xFu;
                        ag0 = __fadd_rn(ag0, (bits & 1u) ? a : 0.f);
                        ag1 = __fadd_rn(ag1, (bits & 2u) ? a : 0.f);
                        ag2 = __fadd_rn(ag2, (bits & 4u) ? a : 0.f);
                        ag3 = __fadd_rn(ag3, (bits & 8u) ? a : 0.f);
                    }
                }

                // LIF update (identical FP sequence to reference)
                float hv[4] = {hs[s].x, hs[s].y, hs[s].z, hs[s].w};
                float vv[4] = {vs[s].x, vs[s].y, vs[s].z, vs[s].w};
                float ag[4] = {ag0, ag1, ag2, ag3};
                float vf[4], sf[4];
                uint32_t rcu = rcs[s], rcn = 0u, nib = 0u;
                #pragma unroll
                for (int q = 0; q < 4; ++q) {
                    float vn = __fadd_rn(__fadd_rn(__fmul_rn(0.8f, vv[q]), hv[q]), ag[q]);
                    uint32_t rc = (rcu >> (8 * q)) & 0xFFu;
                    bool spk = (vn >= 0.5f) && (rc == 0u);
                    vf[q] = spk ? 0.0f : vn;
                    sf[q] = spk ? 1.0f : 0.0f;
                    uint32_t rnew = spk ? 2u : (rc > 0u ? rc - 1u : 0u);
                    rcn |= rnew << (8 * q);
                    nib |= (spk ? 1u : 0u) << q;
                }
                vs[s] = make_float4(vf[0], vf[1], vf[2], vf[3]);
                rcs[s] = rcn;
                size_t idx = (size_t)(n0 + m) * HID + ln * 4;
                *(float4*)&out[NH + (size_t)t * NH + idx] =
                    make_float4(sf[0], sf[1], sf[2], sf[3]);
                if (t == T_STEPS - 1) {
                    *(float4*)&out[idx] = make_float4(
                        __fadd_rn(hv[0], __fmul_rn(0.5f, vf[0])),
                        __fadd_rn(hv[1], __fmul_rn(0.5f, vf[1])),
                        __fadd_rn(hv[2], __fmul_rn(0.5f, vf[2])),
                        __fadd_rn(hv[3], __fmul_rn(0.5f, vf[3])));
                }
                atomicOr(&sbw[m][w], nib << shb);
            }
        }
        __syncthreads();
        for (int i = tid; i < ncnt * 4; i += 256) {   // publish (LLC) + re-zero
            __hip_atomic_store(&nxt[(size_t)n0 * 4 + i], ((uint32_t*)sbw)[i],
                               __ATOMIC_RELAXED, __HIP_MEMORY_SCOPE_AGENT);
            ((uint32_t*)sbw)[i] = 0u;
        }
    }
}

// ---------- multi-kernel fallback step (R2-verified structure, edata form) ----------
__global__ __launch_bounds__(128) void k_step(const int* __restrict__ row_ptr,
                                              const int2* __restrict__ edata,
                                              const uint32_t* __restrict__ sb_cur,
                                              uint32_t* __restrict__ sb_nxt,
                                              float* __restrict__ h,
                                              float* __restrict__ v,
                                              unsigned char* __restrict__ refc,
                                              const unsigned int* __restrict__ mn_e,
                                              const unsigned int* __restrict__ mx_e,
                                              float* __restrict__ out_spk,
                                              float* __restrict__ out_fus,
                                              int t0, int is_last) {
    __shared__ float    attr_l[4][128];
    __shared__ uint32_t words_l[4][128][4];
    __shared__ uint32_t sbw[16];
    __shared__ int      rp[5];

    const int tid = threadIdx.x;
    const int ns = tid >> 5, ln = tid & 31;
    const int nb = blockIdx.x * 4;
    const int n  = nb + ns;

    if (tid < 16) sbw[tid] = 0;
    if (tid < 5)  rp[tid] = row_ptr[nb + tid];
    __syncthreads();

    const int beg = rp[ns], cnt = rp[ns + 1] - beg;
    int cmax = 0;
    #pragma unroll
    for (int q = 0; q < 4; ++q) cmax = max(cmax, rp[q + 1] - rp[q]);
    const int nchunk = (cmax + 127) >> 7;

    float agg0 = 0.f, agg1 = 0.f, agg2 = 0.f, agg3 = 0.f;
    const int w = ln >> 3, shb = (ln & 7) * 4;

    for (int ch = 0; ch < nchunk; ++ch) {
        int base = ch << 7;
        __syncthreads();
        #pragma unroll
        for (int rep = 0; rep < 4; ++rep) {
            int i = base + rep * 32 + ln;
            if (i < cnt) {
                int2 d = edata[beg + i];
                attr_l[ns][rep * 32 + ln] = __int_as_float(d.y);
                *(uint4*)&words_l[ns][rep * 32 + ln][0] =
                    *(const uint4*)&sb_cur[(size_t)d.x * 4];
            }
        }
        __syncthreads();
        int lim = min(128, cnt - base);
        for (int i = 0; i < lim; ++i) {
            uint32_t u = words_l[ns][i][w];
            float a = attr_l[ns][i];
            uint32_t bits = (u >> shb) & 0xFu;
            agg0 = __fadd_rn(agg0, (bits & 1u) ? a : 0.0f);
            agg1 = __fadd_rn(agg1, (bits & 2u) ? a : 0.0f);
            agg2 = __fadd_rn(agg2, (bits & 4u) ? a : 0.0f);
            agg3 = __fadd_rn(agg3, (bits & 8u) ? a : 0.0f);
        }
    }

    const size_t idx = (size_t)n * HID + ln * 4;
    float4 h4 = *(const float4*)&h[idx];
    if (t0) {
        const int jb = ln * 4;
        float hq[4] = {h4.x, h4.y, h4.z, h4.w};
        #pragma unroll
        for (int q = 0; q < 4; ++q) {
            float mn = dec_f(mn_e[jb + q]);
            float mx = dec_f(mx_e[jb + q]);
            float d2 = __fadd_rn(__fsub_rn(mx, mn), 1e-6f);
            hq[q] = __fdiv_rn(__fsub_rn(hq[q], mn), d2);
        }
        h4 = make_float4(hq[0], hq[1], hq[2], hq[3]);
        *(float4*)&h[idx] = h4;
    }
    float4 v4;
    unsigned int rcu;
    if (t0) { v4 = make_float4(0.f, 0.f, 0.f, 0.f); rcu = 0u; }
    else    { v4 = *(const float4*)&v[idx]; rcu = *(const unsigned int*)&refc[idx]; }

    float hv[4]  = {h4.x, h4.y, h4.z, h4.w};
    float vv[4]  = {v4.x, v4.y, v4.z, v4.w};
    float ag[4]  = {agg0, agg1, agg2, agg3};
    float vf[4], sf[4];
    unsigned int rcn = 0u, nib = 0u;
    #pragma unroll
    for (int q = 0; q < 4; ++q) {
        float vn = __fadd_rn(__fadd_rn(__fmul_rn(0.8f, vv[q]), hv[q]), ag[q]);
        unsigned int rc = (rcu >> (8 * q)) & 0xFFu;
        bool spk = (vn >= 0.5f) && (rc == 0u);
        vf[q] = spk ? 0.0f : vn;
        sf[q] = spk ? 1.0f : 0.0f;
        unsigned int rnew = spk ? 2u : (rc > 0u ? rc - 1u : 0u);
        rcn |= rnew << (8 * q);
        nib |= (spk ? 1u : 0u) << q;
    }
    *(float4*)&v[idx] = make_float4(vf[0], vf[1], vf[2], vf[3]);
    *(unsigned int*)&refc[idx] = rcn;
    *(float4*)&out_spk[idx] = make_float4(sf[0], sf[1], sf[2], sf[3]);
    if (is_last) {
        *(float4*)&out_fus[idx] = make_float4(
            __fadd_rn(hv[0], __fmul_rn(0.5f, vf[0])),
            __fadd_rn(hv[1], __fmul_rn(0.5f, vf[1])),
            __fadd_rn(hv[2], __fmul_rn(0.5f, vf[2])),
            __fadd_rn(hv[3], __fmul_rn(0.5f, vf[3])));
    }
    atomicOr(&sbw[ns * 4 + w], nib << shb);
    __syncthreads();
    if (tid < 16)
        sb_nxt[(size_t)(nb + (tid >> 2)) * 4 + (tid & 3)] = sbw[tid];
}

extern "C" void kernel_launch(void* const* d_in, const int* in_sizes, int n_in,
                              void* d_out, int out_size, void* d_ws, size_t ws_size,
                              hipStream_t stream) {
    const float* x          = (const float*)d_in[0];
    const int*   spike_node = (const int*)  d_in[1];
    const int*   edge_index = (const int*)  d_in[2];   // [2][E]
    const float* edge_attr  = (const float*)d_in[4];
    const float* W          = (const float*)d_in[5];
    const float* b          = (const float*)d_in[6];
    float* out = (float*)d_out;

    const int* src = edge_index;
    const int* dst = edge_index + N_EDGES;

    char* wsp = (char*)d_ws;
    auto alloc = [&](size_t bytes) {
        char* p = wsp;
        wsp += (bytes + 255) & ~(size_t)255;
        return p;
    };
    float*         h        = (float*)        alloc((size_t)N_NODES * HID * 4);
    float*         v        = (float*)        alloc((size_t)N_NODES * HID * 4);
    unsigned char* refc     = (unsigned char*)alloc((size_t)N_NODES * HID);
    uint32_t*      sbA      = (uint32_t*)     alloc((size_t)N_NODES * 16);
    uint32_t*      sbB      = (uint32_t*)     alloc((size_t)N_NODES * 16);
    int*           counts   = (int*)          alloc((size_t)N_NODES * 4);
    int*           cursor   = (int*)          alloc((size_t)N_NODES * 4);
    int*           row_tmp  = (int*)          alloc((size_t)N_NODES * 4);
    int*           row_ptr  = (int*)          alloc((size_t)(N_NODES + 1) * 4);
    int*           blocksum = (int*)          alloc(256 * 4);
    int*           blockoff = (int*)          alloc(256 * 4);
    int*           eid      = (int*)          alloc((size_t)N_EDGES * 4);
    int2*          edata    = (int2*)         alloc((size_t)N_EDGES * 8);
    unsigned int*  mn_e     = (unsigned int*) alloc(HID * 4);
    unsigned int*  mx_e     = (unsigned int*) alloc(HID * 4);
    int*           barv     = (int*)          alloc(8192);

    hipMemsetAsync(counts, 0x00, (size_t)N_NODES * 4, stream);
    hipMemsetAsync(cursor, 0x00, (size_t)N_NODES * 4, stream);
    hipMemsetAsync(mn_e,   0xFF, HID * 4, stream);
    hipMemsetAsync(mx_e,   0x00, HID * 4, stream);
    hipMemsetAsync(barv,   0x00, 8192, stream);

    const int NB = (N_NODES + 255) / 256;   // 196
    const int EB = (N_EDGES + 255) / 256;

    k_count<<<EB, 256, 0, stream>>>(dst, counts);
    k_scan1<<<NB, 256, 0, stream>>>(counts, row_tmp, blocksum);
    k_scan2<<<1, 64, 0, stream>>>(blocksum, blockoff, NB, row_ptr);
    k_scan3<<<NB, 256, 0, stream>>>(row_tmp, blockoff, row_ptr);
    k_fill<<<EB, 256, 0, stream>>>(dst, src, edge_attr, row_ptr, cursor, eid, edata);
    k_bsort<<<N_NODES / 4, 256, 0, stream>>>(row_ptr, eid, edata);

    k_gemm<<<(N_NODES + 63) / 64, 256, 0, stream>>>(x, W, b, h, mn_e, mx_e);
    k_init_bits<<<NB, 256, 0, stream>>>(spike_node, sbA);

    const size_t NH = (size_t)N_NODES * HID;

    // variant A: 66 nodes/block, 758 blocks, needs 3 blocks/CU (R6/R1 shape)
    auto kA = k_lif_t<66, 9, 1536, 0, 3>;
    // variant C: 33 nodes/block, 1516 blocks, needs 6 blocks/CU
    auto kC = k_lif_t<33, 5, 768, 0, 6>;
    // variant D: 40 nodes/block, 1250 blocks, needs 5 blocks/CU
    auto kD = k_lif_t<40, 5, 896, 0, 5>;
    // variant B: 98 nodes/block, 511 blocks, needs 2 blocks/CU
    auto kB = k_lif_t<98, 13, 1920, 1, 2>;
    int occA = 0, occC = 0, occD = 0, occB = 0;
    hipOccupancyMaxActiveBlocksPerMultiprocessor(&occA, kA, 256, 0);
    hipOccupancyMaxActiveBlocksPerMultiprocessor(&occC, kC, 256, 0);
    hipOccupancyMaxActiveBlocksPerMultiprocessor(&occD, kD, 256, 0);
    hipOccupancyMaxActiveBlocksPerMultiprocessor(&occB, kB, 256, 0);

    if (occA >= 3) {
        const int grid = (N_NODES + 65) / 66;          // 758 <= 768
        kA<<<grid, 256, 0, stream>>>(row_ptr, edata, sbA, sbB, h, mn_e, mx_e,
                                     out, barv, grid);
    } else if (occC >= 6) {
        const int grid = (N_NODES + 32) / 33;          // 1516 <= 1536
        kC<<<grid, 256, 0, stream>>>(row_ptr, edata, sbA, sbB, h, mn_e, mx_e,
                                     out, barv, grid);
    } else if (occD >= 5) {
        const int grid = (N_NODES + 39) / 40;          // 1250 <= 1280
        kD<<<grid, 256, 0, stream>>>(row_ptr, edata, sbA, sbB, h, mn_e, mx_e,
                                     out, barv, grid);
    } else if (occB >= 2) {
        const int grid = (N_NODES + 97) / 98;          // 511 <= 512
        kB<<<grid, 256, 0, stream>>>(row_ptr, edata, sbA, sbB, h, mn_e, mx_e,
                                     out, barv, grid);
    } else {
        for (int t = 0; t < T_STEPS; ++t) {
            uint32_t* cur = (t & 1) ? sbB : sbA;
            uint32_t* nxt = (t & 1) ? sbA : sbB;
            k_step<<<N_NODES / 4, 128, 0, stream>>>(row_ptr, edata, cur, nxt,
                                                    h, v, refc, mn_e, mx_e,
                                                    out + NH + (size_t)t * NH,
                                                    out, (t == 0) ? 1 : 0,
                                                    (t == T_STEPS - 1) ? 1 : 0);
        }
    }
}

// Round 3
// 618.326 us; speedup vs baseline: 1.0114x; 1.0114x over previous
//
#include <hip/hip_runtime.h>
#include <cstdint>

#define N_NODES 50000
#define N_EDGES 800000
#define IN_DIM  256
#define HID     128
#define T_STEPS 8

#define AG_LOAD(p)     __hip_atomic_load((p), __ATOMIC_RELAXED, __HIP_MEMORY_SCOPE_AGENT)
#define AG_STORE(p, v) __hip_atomic_store((p), (v), __ATOMIC_RELAXED, __HIP_MEMORY_SCOPE_AGENT)
#define AG_ADD(p, v)   __hip_atomic_fetch_add((p), (v), __ATOMIC_RELAXED, __HIP_MEMORY_SCOPE_AGENT)
#define AG_MIN(p, v)   __hip_atomic_fetch_min((p), (v), __ATOMIC_RELAXED, __HIP_MEMORY_SCOPE_AGENT)
#define AG_MAX(p, v)   __hip_atomic_fetch_max((p), (v), __ATOMIC_RELAXED, __HIP_MEMORY_SCOPE_AGENT)

// ---------- float <-> orderable uint encoding for atomic min/max ----------
static __device__ __forceinline__ unsigned int enc_f(float f) {
    unsigned int u = __float_as_uint(f);
    return (u & 0x80000000u) ? ~u : (u | 0x80000000u);
}
static __device__ __forceinline__ float dec_f(unsigned int u) {
    unsigned int b = (u & 0x80000000u) ? (u ^ 0x80000000u) : ~u;
    return __uint_as_float(b);
}

// ---------- flag-array barrier, ZERO fences / ZERO acq_rel (R2-proven) ----------
// All cross-block data moves via RELAXED agent-scope atomics (LLC-homed,
// cross-XCD coherent). __syncthreads drains vmcnt(0) => prior stores/atomics
// are LLC-acked before the flag store; consumers gather only after `go`.
static __device__ __forceinline__ void fbar(int* bar, int nblk, int t) {
    int* flags = bar;            // [nblk] monotone phase ids
    int* go    = bar + 1900;     // separate line
    __syncthreads();
    if (blockIdx.x == 0) {
        if (threadIdx.x == 0) AG_STORE(&flags[0], t);
        for (;;) {
            int ok = 1;
            for (int i = (int)threadIdx.x; i < nblk; i += 256)
                ok &= (AG_LOAD(&flags[i]) >= t);
            if (__syncthreads_and(ok)) break;
            __builtin_amdgcn_s_sleep(1);
        }
        if (threadIdx.x == 0) AG_STORE(go, t);
    } else {
        if (threadIdx.x == 0) {
            AG_STORE(&flags[blockIdx.x], t);
            while (AG_LOAD(go) < t) __builtin_amdgcn_s_sleep(4);
        }
        __syncthreads();
    }
}

// ================== MEGA: whole pipeline in one persistent kernel ==================
// R2 post-mortem: harness dur stuck at ~620us across k_lif_t 628/970/272 profiled
// => non-LIF prep (~15 dispatches: count/scan/fill/bsort/gemm/init + boundary
// drains) costs ~350us. Fuse it all behind the fence-free fbar.
// Phases: 1 init | 2 count | 3 blocksum | 4 row_ptr | 5 fill | (gemm+minmax,
// sort->LDS, spike-init) | 6 | LIF steps with fbar(6+t).
// LDS pool (TECAP*6 words = 36KB) time-sliced: [scan rbuf] [gemm Ws+xs]
// [minmax red] [sort eid_l] then steady-state ed_src/attr/wds.
template<int TNPB, int TNSLOT, int TECAP, int TMINW>
__global__ __launch_bounds__(256, TMINW) void k_mega(
    const float* __restrict__ x,
    const int*   __restrict__ spike_node,
    const int*   __restrict__ esrc,
    const int*   __restrict__ edst,
    const float* __restrict__ eattr,
    const float* __restrict__ W,
    const float* __restrict__ b,
    int* counts, int* cursor, int* row_ptr, int* blocksum,
    int* eid, int2* edata,
    unsigned int* mn_e, unsigned int* mx_e,
    uint32_t* sbA, uint32_t* sbB,
    float* __restrict__ out,
    int* bar, int nblk)
{
    __shared__ int      lrp[TNPB + 1];
    __shared__ uint32_t pool[TECAP * 6];
    __shared__ uint32_t sbw[TNPB][4];

    int*      ed_src_l  = (int*)pool;                 // [TECAP]   steady
    float*    ed_attr_l = (float*)(pool + TECAP);     // [TECAP]   steady
    uint32_t* ed_wds    = pool + 2 * TECAP;           // [TECAP*4] step loop
    int*      eid_l     = (int*)(pool + 5 * TECAP);   // sort keys (transient)
    float*    Ws        = (float*)pool;               // [4096]  gemm (transient)
    float*    xs        = (float*)(pool + 4096);      // [TNPB*36] gemm (transient)
    float*    red_mn    = (float*)pool;               // [1024] minmax (transient)
    float*    red_mx    = (float*)(pool + 1024);      // [1024]
    int*      rbuf      = (int*)pool;                 // [256]  scan (transient)
    int*      cnt_l     = (int*)sbw;                  // [TNPB] scan (transient)

    const int tid = threadIdx.x;
    const int bid = blockIdx.x;
    const int g   = tid >> 5, ln = tid & 31;
    const int n0  = bid * TNPB;
    const int ncnt = min(TNPB, N_NODES - n0);
    const int w = ln >> 3, shb = (ln & 7) * 4;
    const size_t NH = (size_t)N_NODES * HID;

    // ---- P0: zero own counts/cursor; block0 inits mn/mx ----
    for (int i = tid; i < ncnt; i += 256) {
        AG_STORE(&counts[n0 + i], 0);
        AG_STORE(&cursor[n0 + i], 0);
    }
    if (bid == 0 && tid < HID) {
        AG_STORE(&mn_e[tid], 0xFFFFFFFFu);
        AG_STORE(&mx_e[tid], 0u);
    }
    fbar(bar, nblk, 1);

    // ---- P1: degree count ----
    for (int e = bid * 256 + tid; e < N_EDGES; e += nblk * 256)
        AG_ADD(&counts[edst[e]], 1);
    fbar(bar, nblk, 2);

    // ---- P2a: own-range degree sum -> blocksum ----
    for (int i = tid; i < ncnt; i += 256) cnt_l[i] = AG_LOAD(&counts[n0 + i]);
    __syncthreads();
    if (tid == 0) {
        int s = 0;
        for (int i = 0; i < ncnt; ++i) s += cnt_l[i];
        AG_STORE(&blocksum[bid], s);
    }
    fbar(bar, nblk, 3);

    // ---- P2b: exclusive base over blocksums + own row_ptr ----
    {
        int part = 0;
        for (int j = tid; j < bid; j += 256) part += AG_LOAD(&blocksum[j]);
        rbuf[tid] = part;
        __syncthreads();
        for (int off = 128; off > 0; off >>= 1) {
            if (tid < off) rbuf[tid] += rbuf[tid + off];
            __syncthreads();
        }
        if (tid == 0) {
            int run = rbuf[0];
            for (int i = 0; i < ncnt; ++i) { lrp[i] = run; run += cnt_l[i]; }
            lrp[ncnt] = run;
        }
        __syncthreads();
        for (int i = tid; i <= ncnt; i += 256) AG_STORE(&row_ptr[n0 + i], lrp[i]);
    }
    fbar(bar, nblk, 4);

    // ---- P3: fill CSR slots (scatter by dst) ----
    for (int e = bid * 256 + tid; e < N_EDGES; e += nblk * 256) {
        int d  = edst[e];
        int rp = AG_LOAD(&row_ptr[d]);
        int c  = AG_ADD(&cursor[d], 1);
        int p  = rp + c;
        AG_STORE(&eid[p], e);
        unsigned long long pk = (unsigned long long)(unsigned int)esrc[e] |
                                ((unsigned long long)__float_as_uint(eattr[e]) << 32);
        AG_STORE((unsigned long long*)&edata[p], pk);
    }
    fbar(bar, nblk, 5);

    const int ebase = lrp[0];
    const int etot  = lrp[ncnt] - ebase;
    const bool inlds = (etot <= TECAP);

    // ---- P4: GEMM (bit-identical FMA sequence to k_gemm) into hs + minmax ----
    float4 hs[TNSLOT], vs[TNSLOT];
    uint32_t rcs[TNSLOT];
    #pragma unroll
    for (int s = 0; s < TNSLOT; ++s)
        hs[s] = make_float4(0.f, 0.f, 0.f, 0.f);

    int xoff[TNSLOT];
    #pragma unroll
    for (int s = 0; s < TNSLOT; ++s) xoff[s] = min(s * 8 + g, TNPB - 1) * 36;

    for (int kc = 0; kc < IN_DIM; kc += 32) {
        __syncthreads();
        for (int idx = tid; idx < TNPB * 8; idx += 256) {
            int node = idx >> 3, q = idx & 7;
            int row = min(n0 + node, N_NODES - 1);
            *(float4*)&xs[node * 36 + q * 4] =
                *(const float4*)(x + (size_t)row * IN_DIM + kc + q * 4);
        }
        for (int idx = tid; idx < 1024; idx += 256) {
            int r = idx >> 5, c = idx & 31;
            *(float4*)&Ws[r * 128 + c * 4] =
                *(const float4*)(W + (size_t)(kc + r) * HID + c * 4);
        }
        __syncthreads();
        #pragma unroll 4
        for (int k = 0; k < 32; ++k) {
            float4 wf = *(float4*)&Ws[k * 128 + ln * 4];
            #pragma unroll
            for (int s = 0; s < TNSLOT; ++s) {
                float xv = xs[xoff[s] + k];
                hs[s].x = __fmaf_rn(xv, wf.x, hs[s].x);
                hs[s].y = __fmaf_rn(xv, wf.y, hs[s].y);
                hs[s].z = __fmaf_rn(xv, wf.z, hs[s].z);
                hs[s].w = __fmaf_rn(xv, wf.w, hs[s].w);
            }
        }
    }
    {
        float4 bv = *(const float4*)(b + ln * 4);
        float lmn[4], lmx[4];
        #pragma unroll
        for (int c = 0; c < 4; ++c) { lmn[c] = INFINITY; lmx[c] = -INFINITY; }
        #pragma unroll
        for (int s = 0; s < TNSLOT; ++s) {
            hs[s].x = __fadd_rn(hs[s].x, bv.x);
            hs[s].y = __fadd_rn(hs[s].y, bv.y);
            hs[s].z = __fadd_rn(hs[s].z, bv.z);
            hs[s].w = __fadd_rn(hs[s].w, bv.w);
            lmn[0] = fminf(lmn[0], hs[s].x); lmx[0] = fmaxf(lmx[0], hs[s].x);
            lmn[1] = fminf(lmn[1], hs[s].y); lmx[1] = fmaxf(lmx[1], hs[s].y);
            lmn[2] = fminf(lmn[2], hs[s].z); lmx[2] = fmaxf(lmx[2], hs[s].z);
            lmn[3] = fminf(lmn[3], hs[s].w); lmx[3] = fmaxf(lmx[3], hs[s].w);
        }
        __syncthreads();                       // Ws/xs dead
        #pragma unroll
        for (int c = 0; c < 4; ++c) {
            red_mn[g * 128 + ln * 4 + c] = lmn[c];
            red_mx[g * 128 + ln * 4 + c] = lmx[c];
        }
        __syncthreads();
        if (tid < 128) {
            float mnv = red_mn[tid], mxv = red_mx[tid];
            #pragma unroll
            for (int r = 1; r < 8; ++r) {
                mnv = fminf(mnv, red_mn[r * 128 + tid]);
                mxv = fmaxf(mxv, red_mx[r * 128 + tid]);
            }
            AG_MIN(&mn_e[tid], enc_f(mnv));
            AG_MAX(&mx_e[tid], enc_f(mxv));
        }
        __syncthreads();                       // red dead
    }

    // ---- P5: per-node sort by eid (ascending np.add.at order) -> LDS ----
    if (inlds) {
        for (int m = tid >> 6; m < ncnt; m += 4) {
            int l = tid & 63;
            int gbeg = lrp[m], lbeg = gbeg - ebase;
            int cnt = lrp[m + 1] - gbeg;
            if (cnt <= 0) continue;
            if (cnt <= 64) {
                int key = 0x7FFFFFFF, sv = 0, av = 0;
                if (l < cnt) {
                    key = AG_LOAD(&eid[gbeg + l]);
                    unsigned long long pk =
                        AG_LOAD((unsigned long long*)&edata[gbeg + l]);
                    sv = (int)(unsigned int)pk;
                    av = (int)(unsigned int)(pk >> 32);
                }
                #pragma unroll
                for (int k = 2; k <= 64; k <<= 1) {
                    for (int j = k >> 1; j > 0; j >>= 1) {
                        int pk2 = __shfl_xor(key, j);
                        int ps  = __shfl_xor(sv, j);
                        int pa  = __shfl_xor(av, j);
                        bool lower = (l & j) == 0;
                        bool asc   = (l & k) == 0;
                        bool take  = (lower == asc) ? (pk2 < key) : (pk2 > key);
                        if (take) { key = pk2; sv = ps; av = pa; }
                    }
                }
                if (l < cnt) {
                    ed_src_l[lbeg + l]  = sv;
                    ed_attr_l[lbeg + l] = __int_as_float(av);
                }
            } else {
                if (l == 0) {          // robustness path; dead for this input
                    for (int i = 1; i < cnt; ++i) {
                        int ke = AG_LOAD(&eid[gbeg + i]);
                        unsigned long long kd =
                            AG_LOAD((unsigned long long*)&edata[gbeg + i]);
                        int mm = i - 1;
                        while (mm >= 0) {
                            int km = AG_LOAD(&eid[gbeg + mm]);
                            if (km <= ke) break;
                            AG_STORE(&eid[gbeg + mm + 1], km);
                            AG_STORE((unsigned long long*)&edata[gbeg + mm + 1],
                                     AG_LOAD((unsigned long long*)&edata[gbeg + mm]));
                            --mm;
                        }
                        AG_STORE(&eid[gbeg + mm + 1], ke);
                        AG_STORE((unsigned long long*)&edata[gbeg + mm + 1], kd);
                    }
                }
                for (int i = l; i < cnt; i += 64) {
                    unsigned long long pk =
                        AG_LOAD((unsigned long long*)&edata[gbeg + i]);
                    ed_src_l[lbeg + i]  = (int)(unsigned int)pk;
                    ed_attr_l[lbeg + i] = __uint_as_float((unsigned int)(pk >> 32));
                }
            }
        }
    } else {                           // overflow: sort global in place
        for (int m = tid >> 6; m < ncnt; m += 4) {
            int l = tid & 63;
            int gbeg = lrp[m];
            int cnt = lrp[m + 1] - gbeg;
            if (cnt <= 1) continue;
            if (cnt <= 64) {
                int key = 0x7FFFFFFF, sv = 0, av = 0;
                if (l < cnt) {
                    key = AG_LOAD(&eid[gbeg + l]);
                    unsigned long long pk =
                        AG_LOAD((unsigned long long*)&edata[gbeg + l]);
                    sv = (int)(unsigned int)pk;
                    av = (int)(unsigned int)(pk >> 32);
                }
                #pragma unroll
                for (int k = 2; k <= 64; k <<= 1) {
                    for (int j = k >> 1; j > 0; j >>= 1) {
                        int pk2 = __shfl_xor(key, j);
                        int ps  = __shfl_xor(sv, j);
                        int pa  = __shfl_xor(av, j);
                        bool lower = (l & j) == 0;
                        bool asc   = (l & k) == 0;
                        bool take  = (lower == asc) ? (pk2 < key) : (pk2 > key);
                        if (take) { key = pk2; sv = ps; av = pa; }
                    }
                }
                if (l < cnt) {
                    unsigned long long pk =
                        (unsigned long long)(unsigned int)sv |
                        ((unsigned long long)(unsigned int)av << 32);
                    AG_STORE((unsigned long long*)&edata[gbeg + l], pk);
                }
            } else if (l == 0) {
                for (int i = 1; i < cnt; ++i) {
                    int ke = AG_LOAD(&eid[gbeg + i]);
                    unsigned long long kd =
                        AG_LOAD((unsigned long long*)&edata[gbeg + i]);
                    int mm = i - 1;
                    while (mm >= 0) {
                        int km = AG_LOAD(&eid[gbeg + mm]);
                        if (km <= ke) break;
                        AG_STORE(&eid[gbeg + mm + 1], km);
                        AG_STORE((unsigned long long*)&edata[gbeg + mm + 1],
                                 AG_LOAD((unsigned long long*)&edata[gbeg + mm]));
                        --mm;
                    }
                    AG_STORE(&eid[gbeg + mm + 1], ke);
                    AG_STORE((unsigned long long*)&edata[gbeg + mm + 1], kd);
                }
            }
        }
    }

    // ---- P5b: spike-bit init (own nodes) + zero sbw ----
    for (int i = tid; i < ncnt; i += 256) {
        uint32_t f = spike_node[n0 + i] ? 0xFFFFFFFFu : 0u;
        unsigned long long ff = (unsigned long long)f | ((unsigned long long)f << 32);
        AG_STORE((unsigned long long*)&sbA[(size_t)(n0 + i) * 4], ff);
        AG_STORE((unsigned long long*)&sbA[(size_t)(n0 + i) * 4 + 2], ff);
    }
    for (int i = tid; i < ncnt * 4; i += 256) ((uint32_t*)sbw)[i] = 0u;
    fbar(bar, nblk, 6);

    // ---- normalize hs (identical FP sequence to prior h-load path) ----
    {
        float mn0 = dec_f(AG_LOAD(&mn_e[ln * 4 + 0]));
        float mn1 = dec_f(AG_LOAD(&mn_e[ln * 4 + 1]));
        float mn2 = dec_f(AG_LOAD(&mn_e[ln * 4 + 2]));
        float mn3 = dec_f(AG_LOAD(&mn_e[ln * 4 + 3]));
        float dd0 = __fadd_rn(__fsub_rn(dec_f(AG_LOAD(&mx_e[ln * 4 + 0])), mn0), 1e-6f);
        float dd1 = __fadd_rn(__fsub_rn(dec_f(AG_LOAD(&mx_e[ln * 4 + 1])), mn1), 1e-6f);
        float dd2 = __fadd_rn(__fsub_rn(dec_f(AG_LOAD(&mx_e[ln * 4 + 2])), mn2), 1e-6f);
        float dd3 = __fadd_rn(__fsub_rn(dec_f(AG_LOAD(&mx_e[ln * 4 + 3])), mn3), 1e-6f);
        #pragma unroll
        for (int s = 0; s < TNSLOT; ++s) {
            hs[s].x = __fdiv_rn(__fsub_rn(hs[s].x, mn0), dd0);
            hs[s].y = __fdiv_rn(__fsub_rn(hs[s].y, mn1), dd1);
            hs[s].z = __fdiv_rn(__fsub_rn(hs[s].z, mn2), dd2);
            hs[s].w = __fdiv_rn(__fsub_rn(hs[s].w, mn3), dd3);
        }
    }
    #pragma unroll
    for (int s = 0; s < TNSLOT; ++s) {
        vs[s] = make_float4(0.f, 0.f, 0.f, 0.f);
        rcs[s] = 0u;
    }

    // ---- 8-step LIF (R2-proven structure) ----
    for (int t = 0; t < T_STEPS; ++t) {
        const uint32_t* cur = (t & 1) ? sbB : sbA;
        uint32_t*       nxt = (t & 1) ? sbA : sbB;
        if (t > 0) fbar(bar, nblk, 6 + t);

        if (inlds) {
            for (int i = tid; i < etot; i += 256) {
                unsigned long long* sp =
                    (unsigned long long*)&cur[(size_t)ed_src_l[i] * 4];
                unsigned long long lo = AG_LOAD(sp);
                unsigned long long hi = AG_LOAD(sp + 1);
                uint4 wv;
                wv.x = (uint32_t)lo; wv.y = (uint32_t)(lo >> 32);
                wv.z = (uint32_t)hi; wv.w = (uint32_t)(hi >> 32);
                *(uint4*)&ed_wds[i * 4] = wv;
            }
        }
        __syncthreads();

        #pragma unroll
        for (int s = 0; s < TNSLOT; ++s) {
            int m = s * 8 + g;
            if (m < ncnt) {
                float ag0 = 0.f, ag1 = 0.f, ag2 = 0.f, ag3 = 0.f;
                if (inlds) {
                    int lb = lrp[m] - ebase, le = lrp[m + 1] - ebase;
                    for (int i = lb; i < le; ++i) {       // ascending edge order
                        uint32_t u = ed_wds[i * 4 + w];
                        float a = ed_attr_l[i];
                        uint32_t bits = (u >> shb) & 0xFu;
                        ag0 = __fadd_rn(ag0, (bits & 1u) ? a : 0.f);
                        ag1 = __fadd_rn(ag1, (bits & 2u) ? a : 0.f);
                        ag2 = __fadd_rn(ag2, (bits & 4u) ? a : 0.f);
                        ag3 = __fadd_rn(ag3, (bits & 8u) ? a : 0.f);
                    }
                } else {
                    int lb = lrp[m], le = lrp[m + 1];
                    for (int i = lb; i < le; ++i) {
                        unsigned long long pk =
                            AG_LOAD((unsigned long long*)&edata[i]);
                        int srcn = (int)(unsigned int)pk;
                        float a = __uint_as_float((unsigned int)(pk >> 32));
                        uint32_t u = AG_LOAD((uint32_t*)&cur[(size_t)srcn * 4 + w]);
                        uint32_t bits = (u >> shb) & 0xFu;
                        ag0 = __fadd_rn(ag0, (bits & 1u) ? a : 0.f);
                        ag1 = __fadd_rn(ag1, (bits & 2u) ? a : 0.f);
                        ag2 = __fadd_rn(ag2, (bits & 4u) ? a : 0.f);
                        ag3 = __fadd_rn(ag3, (bits & 8u) ? a : 0.f);
                    }
                }

                float hv[4] = {hs[s].x, hs[s].y, hs[s].z, hs[s].w};
                float vv[4] = {vs[s].x, vs[s].y, vs[s].z, vs[s].w};
                float ag[4] = {ag0, ag1, ag2, ag3};
                float vf[4], sf[4];
                uint32_t rcu = rcs[s], rcn = 0u, nib = 0u;
                #pragma unroll
                for (int q = 0; q < 4; ++q) {
                    float vn = __fadd_rn(__fadd_rn(__fmul_rn(0.8f, vv[q]), hv[q]), ag[q]);
                    uint32_t rc = (rcu >> (8 * q)) & 0xFFu;
                    bool spk = (vn >= 0.5f) && (rc == 0u);
                    vf[q] = spk ? 0.0f : vn;
                    sf[q] = spk ? 1.0f : 0.0f;
                    uint32_t rnew = spk ? 2u : (rc > 0u ? rc - 1u : 0u);
                    rcn |= rnew << (8 * q);
                    nib |= (spk ? 1u : 0u) << q;
                }
                vs[s] = make_float4(vf[0], vf[1], vf[2], vf[3]);
                rcs[s] = rcn;
                size_t idx = (size_t)(n0 + m) * HID + ln * 4;
                *(float4*)&out[NH + (size_t)t * NH + idx] =
                    make_float4(sf[0], sf[1], sf[2], sf[3]);
                if (t == T_STEPS - 1) {
                    *(float4*)&out[idx] = make_float4(
                        __fadd_rn(hv[0], __fmul_rn(0.5f, vf[0])),
                        __fadd_rn(hv[1], __fmul_rn(0.5f, vf[1])),
                        __fadd_rn(hv[2], __fmul_rn(0.5f, vf[2])),
                        __fadd_rn(hv[3], __fmul_rn(0.5f, vf[3])));
                }
                atomicOr(&sbw[m][w], nib << shb);
            }
        }
        __syncthreads();
        for (int i = tid; i < ncnt * 4; i += 256) {
            AG_STORE(&nxt[(size_t)n0 * 4 + i], ((uint32_t*)sbw)[i]);
            ((uint32_t*)sbw)[i] = 0u;
        }
    }
}

// ================== fallback pipeline (unchanged, R2-proven) ==================
__global__ void k_count(const int* __restrict__ dst, int* __restrict__ counts) {
    int e = blockIdx.x * blockDim.x + threadIdx.x;
    if (e < N_EDGES) atomicAdd(&counts[dst[e]], 1);
}

__global__ void k_scan1(const int* __restrict__ counts, int* __restrict__ row_tmp,
                        int* __restrict__ blocksum) {
    __shared__ int sh[256];
    int t = threadIdx.x, i = blockIdx.x * 256 + t;
    int c = (i < N_NODES) ? counts[i] : 0;
    sh[t] = c; __syncthreads();
    for (int off = 1; off < 256; off <<= 1) {
        int val = (t >= off) ? sh[t - off] : 0;
        __syncthreads();
        sh[t] += val;
        __syncthreads();
    }
    if (i < N_NODES) row_tmp[i] = sh[t] - c;
    if (t == 255) blocksum[blockIdx.x] = sh[255];
}

__global__ void k_scan2(const int* __restrict__ blocksum, int* __restrict__ blockoff,
                        int nb, int* __restrict__ row_ptr) {
    if (threadIdx.x == 0) {
        int acc = 0;
        for (int b = 0; b < nb; ++b) { blockoff[b] = acc; acc += blocksum[b]; }
        row_ptr[N_NODES] = acc;
    }
}

__global__ void k_scan3(const int* __restrict__ row_tmp, const int* __restrict__ blockoff,
                        int* __restrict__ row_ptr) {
    int i = blockIdx.x * blockDim.x + threadIdx.x;
    if (i < N_NODES) row_ptr[i] = row_tmp[i] + blockoff[i >> 8];
}

__global__ void k_fill(const int* __restrict__ dst, const int* __restrict__ src,
                       const float* __restrict__ attr,
                       const int* __restrict__ row_ptr, int* __restrict__ cursor,
                       int* __restrict__ eid, int2* __restrict__ edata) {
    int e = blockIdx.x * blockDim.x + threadIdx.x;
    if (e >= N_EDGES) return;
    int d = dst[e];
    int p = row_ptr[d] + atomicAdd(&cursor[d], 1);
    eid[p]   = e;
    edata[p] = make_int2(src[e], __float_as_int(attr[e]));
}

__global__ __launch_bounds__(256) void k_bsort(const int* __restrict__ row_ptr,
                                               int* __restrict__ eid,
                                               int2* __restrict__ edata) {
    int node = blockIdx.x * 4 + (threadIdx.x >> 6);
    int l = threadIdx.x & 63;
    int beg = row_ptr[node], end = row_ptr[node + 1], cnt = end - beg;
    if (cnt <= 1) return;
    if (cnt <= 64) {
        int key = 0x7FFFFFFF, sv = 0, av = 0;
        if (l < cnt) { key = eid[beg + l]; int2 d = edata[beg + l]; sv = d.x; av = d.y; }
        #pragma unroll
        for (int k = 2; k <= 64; k <<= 1) {
            for (int j = k >> 1; j > 0; j >>= 1) {
                int pk = __shfl_xor(key, j);
                int ps = __shfl_xor(sv, j);
                int pa = __shfl_xor(av, j);
                bool lower = (l & j) == 0;
                bool asc   = (l & k) == 0;
                bool take = (lower == asc) ? (pk < key) : (pk > key);
                if (take) { key = pk; sv = ps; av = pa; }
            }
        }
        if (l < cnt) { eid[beg + l] = key; edata[beg + l] = make_int2(sv, av); }
    } else if (l == 0) {
        for (int i = beg + 1; i < end; ++i) {
            int ke = eid[i]; int2 kd = edata[i];
            int m = i - 1;
            while (m >= beg && eid[m] > ke) {
                eid[m+1] = eid[m]; edata[m+1] = edata[m]; --m;
            }
            eid[m+1] = ke; edata[m+1] = kd;
        }
    }
}

__global__ __launch_bounds__(256) void k_gemm(const float* __restrict__ x,
                                              const float* __restrict__ W,
                                              const float* __restrict__ b,
                                              float* __restrict__ h,
                                              unsigned int* __restrict__ mn_e,
                                              unsigned int* __restrict__ mx_e) {
    __shared__ float Ws[32 * 128];
    __shared__ float xs[64 * 36];
    __shared__ float red_mn[8 * 128];
    __shared__ float red_mx[8 * 128];
    const int tid = threadIdx.x;
    const int n0 = blockIdx.x * 64;
    const int jt = tid & 31, nt = tid >> 5;
    const int j0 = jt * 4;

    float acc[8][4];
    #pragma unroll
    for (int a = 0; a < 8; ++a)
        #pragma unroll
        for (int c = 0; c < 4; ++c) acc[a][c] = 0.0f;

    const int ldn = tid >> 2;
    const int kq  = (tid & 3) * 8;
    const int xrow = (n0 + ldn < N_NODES) ? (n0 + ldn) : (N_NODES - 1);
    const float* xg = x + (size_t)xrow * IN_DIM;

    for (int kc = 0; kc < IN_DIM; kc += 32) {
        __syncthreads();
        float4 xa = *(const float4*)(xg + kc + kq);
        float4 xb = *(const float4*)(xg + kc + kq + 4);
        *(float4*)&xs[ldn * 36 + kq]     = xa;
        *(float4*)&xs[ldn * 36 + kq + 4] = xb;
        #pragma unroll
        for (int p = 0; p < 4; ++p) {
            int r = nt + p * 8;
            *(float4*)&Ws[r * 128 + j0] =
                *(const float4*)(W + (size_t)(kc + r) * HID + j0);
        }
        __syncthreads();
        const float* xbase = &xs[nt * 8 * 36];
        #pragma unroll 4
        for (int k = 0; k < 32; ++k) {
            float4 wf = *(const float4*)&Ws[k * 128 + j0];
            #pragma unroll
            for (int ni = 0; ni < 8; ++ni) {
                float xv = xbase[ni * 36 + k];
                acc[ni][0] = __fmaf_rn(xv, wf.x, acc[ni][0]);
                acc[ni][1] = __fmaf_rn(xv, wf.y, acc[ni][1]);
                acc[ni][2] = __fmaf_rn(xv, wf.z, acc[ni][2]);
                acc[ni][3] = __fmaf_rn(xv, wf.w, acc[ni][3]);
            }
        }
    }

    float4 bv = *(const float4*)(b + j0);
    float lmn[4], lmx[4];
    #pragma unroll
    for (int c = 0; c < 4; ++c) { lmn[c] = INFINITY; lmx[c] = -INFINITY; }
    #pragma unroll
    for (int ni = 0; ni < 8; ++ni) {
        acc[ni][0] = __fadd_rn(acc[ni][0], bv.x);
        acc[ni][1] = __fadd_rn(acc[ni][1], bv.y);
        acc[ni][2] = __fadd_rn(acc[ni][2], bv.z);
        acc[ni][3] = __fadd_rn(acc[ni][3], bv.w);
        #pragma unroll
        for (int c = 0; c < 4; ++c) {
            lmn[c] = fminf(lmn[c], acc[ni][c]);
            lmx[c] = fmaxf(lmx[c], acc[ni][c]);
        }
    }
    #pragma unroll
    for (int c = 0; c < 4; ++c) {
        red_mn[nt * 128 + j0 + c] = lmn[c];
        red_mx[nt * 128 + j0 + c] = lmx[c];
    }
    __syncthreads();
    if (tid < 128) {
        float mnv = red_mn[tid], mxv = red_mx[tid];
        #pragma unroll
        for (int r = 1; r < 8; ++r) {
            mnv = fminf(mnv, red_mn[r * 128 + tid]);
            mxv = fmaxf(mxv, red_mx[r * 128 + tid]);
        }
        atomicMin(&mn_e[tid], enc_f(mnv));
        atomicMax(&mx_e[tid], enc_f(mxv));
    }
    #pragma unroll
    for (int ni = 0; ni < 8; ++ni) {
        int n = n0 + nt * 8 + ni;
        if (n < N_NODES)
            *(float4*)&h[(size_t)n * HID + j0] =
                make_float4(acc[ni][0], acc[ni][1], acc[ni][2], acc[ni][3]);
    }
}

__global__ void k_init_bits(const int* __restrict__ spike_node, uint32_t* __restrict__ sb) {
    int n = blockIdx.x * blockDim.x + threadIdx.x;
    if (n >= N_NODES) return;
    uint32_t f = spike_node[n] ? 0xFFFFFFFFu : 0u;
    sb[(size_t)n * 4 + 0] = f;
    sb[(size_t)n * 4 + 1] = f;
    sb[(size_t)n * 4 + 2] = f;
    sb[(size_t)n * 4 + 3] = f;
}

__global__ __launch_bounds__(128) void k_step(const int* __restrict__ row_ptr,
                                              const int2* __restrict__ edata,
                                              const uint32_t* __restrict__ sb_cur,
                                              uint32_t* __restrict__ sb_nxt,
                                              float* __restrict__ h,
                                              float* __restrict__ v,
                                              unsigned char* __restrict__ refc,
                                              const unsigned int* __restrict__ mn_e,
                                              const unsigned int* __restrict__ mx_e,
                                              float* __restrict__ out_spk,
                                              float* __restrict__ out_fus,
                                              int t0, int is_last) {
    __shared__ float    attr_l[4][128];
    __shared__ uint32_t words_l[4][128][4];
    __shared__ uint32_t sbw[16];
    __shared__ int      rp[5];

    const int tid = threadIdx.x;
    const int ns = tid >> 5, ln = tid & 31;
    const int nb = blockIdx.x * 4;
    const int n  = nb + ns;

    if (tid < 16) sbw[tid] = 0;
    if (tid < 5)  rp[tid] = row_ptr[nb + tid];
    __syncthreads();

    const int beg = rp[ns], cnt = rp[ns + 1] - beg;
    int cmax = 0;
    #pragma unroll
    for (int q = 0; q < 4; ++q) cmax = max(cmax, rp[q + 1] - rp[q]);
    const int nchunk = (cmax + 127) >> 7;

    float agg0 = 0.f, agg1 = 0.f, agg2 = 0.f, agg3 = 0.f;
    const int w = ln >> 3, shb = (ln & 7) * 4;

    for (int ch = 0; ch < nchunk; ++ch) {
        int base = ch << 7;
        __syncthreads();
        #pragma unroll
        for (int rep = 0; rep < 4; ++rep) {
            int i = base + rep * 32 + ln;
            if (i < cnt) {
                int2 d = edata[beg + i];
                attr_l[ns][rep * 32 + ln] = __int_as_float(d.y);
                *(uint4*)&words_l[ns][rep * 32 + ln][0] =
                    *(const uint4*)&sb_cur[(size_t)d.x * 4];
            }
        }
        __syncthreads();
        int lim = min(128, cnt - base);
        for (int i = 0; i < lim; ++i) {
            uint32_t u = words_l[ns][i][w];
            float a = attr_l[ns][i];
            uint32_t bits = (u >> shb) & 0xFu;
            agg0 = __fadd_rn(agg0, (bits & 1u) ? a : 0.0f);
            agg1 = __fadd_rn(agg1, (bits & 2u) ? a : 0.0f);
            agg2 = __fadd_rn(agg2, (bits & 4u) ? a : 0.0f);
            agg3 = __fadd_rn(agg3, (bits & 8u) ? a : 0.0f);
        }
    }

    const size_t idx = (size_t)n * HID + ln * 4;
    float4 h4 = *(const float4*)&h[idx];
    if (t0) {
        const int jb = ln * 4;
        float hq[4] = {h4.x, h4.y, h4.z, h4.w};
        #pragma unroll
        for (int q = 0; q < 4; ++q) {
            float mn = dec_f(mn_e[jb + q]);
            float mx = dec_f(mx_e[jb + q]);
            float d2 = __fadd_rn(__fsub_rn(mx, mn), 1e-6f);
            hq[q] = __fdiv_rn(__fsub_rn(hq[q], mn), d2);
        }
        h4 = make_float4(hq[0], hq[1], hq[2], hq[3]);
        *(float4*)&h[idx] = h4;
    }
    float4 v4;
    unsigned int rcu;
    if (t0) { v4 = make_float4(0.f, 0.f, 0.f, 0.f); rcu = 0u; }
    else    { v4 = *(const float4*)&v[idx]; rcu = *(const unsigned int*)&refc[idx]; }

    float hv[4]  = {h4.x, h4.y, h4.z, h4.w};
    float vv[4]  = {v4.x, v4.y, v4.z, v4.w};
    float ag[4]  = {agg0, agg1, agg2, agg3};
    float vf[4], sf[4];
    unsigned int rcn = 0u, nib = 0u;
    #pragma unroll
    for (int q = 0; q < 4; ++q) {
        float vn = __fadd_rn(__fadd_rn(__fmul_rn(0.8f, vv[q]), hv[q]), ag[q]);
        unsigned int rc = (rcu >> (8 * q)) & 0xFFu;
        bool spk = (vn >= 0.5f) && (rc == 0u);
        vf[q] = spk ? 0.0f : vn;
        sf[q] = spk ? 1.0f : 0.0f;
        unsigned int rnew = spk ? 2u : (rc > 0u ? rc - 1u : 0u);
        rcn |= rnew << (8 * q);
        nib |= (spk ? 1u : 0u) << q;
    }
    *(float4*)&v[idx] = make_float4(vf[0], vf[1], vf[2], vf[3]);
    *(unsigned int*)&refc[idx] = rcn;
    *(float4*)&out_spk[idx] = make_float4(sf[0], sf[1], sf[2], sf[3]);
    if (is_last) {
        *(float4*)&out_fus[idx] = make_float4(
            __fadd_rn(hv[0], __fmul_rn(0.5f, vf[0])),
            __fadd_rn(hv[1], __fmul_rn(0.5f, vf[1])),
            __fadd_rn(hv[2], __fmul_rn(0.5f, vf[2])),
            __fadd_rn(hv[3], __fmul_rn(0.5f, vf[3])));
    }
    atomicOr(&sbw[ns * 4 + w], nib << shb);
    __syncthreads();
    if (tid < 16)
        sb_nxt[(size_t)(nb + (tid >> 2)) * 4 + (tid & 3)] = sbw[tid];
}

extern "C" void kernel_launch(void* const* d_in, const int* in_sizes, int n_in,
                              void* d_out, int out_size, void* d_ws, size_t ws_size,
                              hipStream_t stream) {
    const float* x          = (const float*)d_in[0];
    const int*   spike_node = (const int*)  d_in[1];
    const int*   edge_index = (const int*)  d_in[2];   // [2][E]
    const float* edge_attr  = (const float*)d_in[4];
    const float* W          = (const float*)d_in[5];
    const float* b          = (const float*)d_in[6];
    float* out = (float*)d_out;

    const int* src = edge_index;
    const int* dst = edge_index + N_EDGES;

    char* wsp = (char*)d_ws;
    auto alloc = [&](size_t bytes) {
        char* p = wsp;
        wsp += (bytes + 255) & ~(size_t)255;
        return p;
    };
    float*         h        = (float*)        alloc((size_t)N_NODES * HID * 4);
    float*         v        = (float*)        alloc((size_t)N_NODES * HID * 4);
    unsigned char* refc     = (unsigned char*)alloc((size_t)N_NODES * HID);
    uint32_t*      sbA      = (uint32_t*)     alloc((size_t)N_NODES * 16);
    uint32_t*      sbB      = (uint32_t*)     alloc((size_t)N_NODES * 16);
    int*           counts   = (int*)          alloc((size_t)N_NODES * 4);
    int*           cursor   = (int*)          alloc((size_t)N_NODES * 4);
    int*           row_tmp  = (int*)          alloc((size_t)N_NODES * 4);
    int*           row_ptr  = (int*)          alloc((size_t)(N_NODES + 1) * 4);
    int*           blocksum = (int*)          alloc(1024 * 4);
    int*           blockoff = (int*)          alloc(1024 * 4);
    int*           eid      = (int*)          alloc((size_t)N_EDGES * 4);
    int2*          edata    = (int2*)         alloc((size_t)N_EDGES * 8);
    unsigned int*  mn_e     = (unsigned int*) alloc(HID * 4);
    unsigned int*  mx_e     = (unsigned int*) alloc(HID * 4);
    int*           barv     = (int*)          alloc(8192);

    const int NB = (N_NODES + 255) / 256;
    const int EB = (N_EDGES + 255) / 256;
    const size_t NH = (size_t)N_NODES * HID;

    auto kM = k_mega<66, 9, 1536, 3>;
    int occM = 0;
    hipOccupancyMaxActiveBlocksPerMultiprocessor(&occM, kM, 256, 0);

    if (occM >= 3) {
        hipMemsetAsync(barv, 0x00, 8192, stream);
        const int grid = (N_NODES + 65) / 66;          // 758 <= 768
        kM<<<grid, 256, 0, stream>>>(x, spike_node, src, dst, edge_attr, W, b,
                                     counts, cursor, row_ptr, blocksum,
                                     eid, edata, mn_e, mx_e, sbA, sbB,
                                     out, barv, grid);
        return;
    }

    // ---------- fallback: R2 pipeline ----------
    hipMemsetAsync(counts, 0x00, (size_t)N_NODES * 4, stream);
    hipMemsetAsync(cursor, 0x00, (size_t)N_NODES * 4, stream);
    hipMemsetAsync(mn_e,   0xFF, HID * 4, stream);
    hipMemsetAsync(mx_e,   0x00, HID * 4, stream);
    hipMemsetAsync(barv,   0x00, 8192, stream);

    k_count<<<EB, 256, 0, stream>>>(dst, counts);
    k_scan1<<<NB, 256, 0, stream>>>(counts, row_tmp, blocksum);
    k_scan2<<<1, 64, 0, stream>>>(blocksum, blockoff, NB, row_ptr);
    k_scan3<<<NB, 256, 0, stream>>>(row_tmp, blockoff, row_ptr);
    k_fill<<<EB, 256, 0, stream>>>(dst, src, edge_attr, row_ptr, cursor, eid, edata);
    k_bsort<<<N_NODES / 4, 256, 0, stream>>>(row_ptr, eid, edata);
    k_gemm<<<(N_NODES + 63) / 64, 256, 0, stream>>>(x, W, b, h, mn_e, mx_e);
    k_init_bits<<<NB, 256, 0, stream>>>(spike_node, sbA);

    for (int t = 0; t < T_STEPS; ++t) {
        uint32_t* cur = (t & 1) ? sbB : sbA;
        uint32_t* nxt = (t & 1) ? sbA : sbB;
        k_step<<<N_NODES / 4, 128, 0, stream>>>(row_ptr, edata, cur, nxt,
                                                h, v, refc, mn_e, mx_e,
                                                out + NH + (size_t)t * NH,
                                                out, (t == 0) ? 1 : 0,
                                                (t == T_STEPS - 1) ? 1 : 0);
    }
}